// Round 10
// baseline (4407.652 us; speedup 1.0000x reference)
//
#include <hip/hip_runtime.h>

// GRU_10746008175428 round 10: de-phased dual-group blocks.
// B=512 T=512 E=64 H=128 P=96.
// 32 blocks x 1024 thr (16 waves, 4/SIMD). Each block = TWO batch groups
// (waves 0-7 = g0, 8-15 = g1) offset by HALF A STEP:
//   HP1: g0 phase-A(t)   | g1 phase-B(t-1)
//   HP2: g0 phase-B(t)   | g1 phase-A(t)       (4 half-phases per 2 steps)
// phase-A = {ds_read h, x-MFMA, hh-MFMA, x prefetch}  (LDS+MFMA pipes)
// phase-B = {gates, ds_write h, h1 global store}      (trans+VALU pipes)
// -> pipes overlap across groups instead of block-serializing per phase.
// Blocks 0-15 producers (layer 0), 16-31 consumers (layer 1 + fused head),
// same-XCD pairs. Agent acquire/release handoff per group (32 counters),
// publish every 8 steps + final T. Per-group math identical to r9.

#define B_SZ 512
#define T_SZ 512
#define E_SZ 64
#define H_SZ 128
#define P_SZ 96
#define NB   16
#define NGRP (B_SZ / NB)          // 32 groups
#define SC_SIG  (-1.44269504f)   // -log2(e)
#define SC_TANH (-2.88539008f)   // -2*log2(e)

typedef _Float16 half8 __attribute__((ext_vector_type(8)));
typedef float    f32x4 __attribute__((ext_vector_type(4)));

__device__ __forceinline__ float exp2_(float x) {
#if __has_builtin(__builtin_amdgcn_exp2f)
    return __builtin_amdgcn_exp2f(x);
#else
    return exp2f(x);
#endif
}
__device__ __forceinline__ float rcp_(float x) {
#if __has_builtin(__builtin_amdgcn_rcpf)
    return __builtin_amdgcn_rcpf(x);
#else
    return 1.0f / x;
#endif
}

// XOR-swizzled byte offset in a [rows][256B] LDS tile
__device__ __forceinline__ int swz256(int row, int byte) {
    return row * 256 + (byte ^ ((row & 7) << 4));
}

// One B-fragment (16 cols x 32 k) from fp32 weight matrix W, pre-scaled.
__device__ __forceinline__ void load_bfrag(const float* __restrict__ W, int ldk,
                                           int n0, int kt, int ln, float scale,
                                           half8* hi) {
    int n = n0 + (ln & 15);
    int k = kt * 32 + (ln >> 4) * 8;
    const float* p = W + (size_t)n * ldk + k;
    float4 a = *(const float4*)p;
    float4 b = *(const float4*)(p + 4);
    float v[8] = {a.x, a.y, a.z, a.w, b.x, b.y, b.z, b.w};
    half8 h;
    #pragma unroll
    for (int j = 0; j < 8; ++j)
        h[j] = (_Float16)(v[j] * scale);
    *hi = h;
}

#define LOADX(Sx, tt)                                                              \
    if ((tt) < T_SZ) {                                                             \
        _Pragma("unroll") for (int kt = 0; kt < KFX; ++kt)                         \
            Sx[kt] = *(const half8*)(xlane + (size_t)(tt) * ROWB + kt * 64);       \
    }

// Phase A: all MFMAs for step tcur + x prefetch (tcur+2). Leaves ax0/ax1
// (r,z pre-acts), ax2 (n x-part), cNH (n hh-part) live for phase B.
#define GRU_A(Sx, tcur)                                                            \
    {                                                                              \
        if (ROLE == 1 && (((tcur) & 1) == 0) && avail < T_SZ) {                    \
            const int need = ((tcur) + 4 < T_SZ) ? (tcur) + 4 : T_SZ;              \
            while (avail < need) {                                                 \
                avail = __hip_atomic_load(prog, __ATOMIC_ACQUIRE,                  \
                                          __HIP_MEMORY_SCOPE_AGENT);               \
                if (avail < need) __builtin_amdgcn_s_sleep(8);                     \
            }                                                                      \
        }                                                                          \
        const char* hb = hs[(tcur) & 1];                                           \
        half8 ah[4];                                                               \
        _Pragma("unroll") for (int kt = 0; kt < 4; ++kt)                           \
            ah[kt] = *(const half8*)(hb + swz256(colg, kt * 64 + rgrp * 16));      \
        ax0 = (f32x4){bs0, bs0, bs0, bs0};                                         \
        ax1 = (f32x4){bs1, bs1, bs1, bs1};                                         \
        ax2 = (f32x4){bi2s, bi2s, bi2s, bi2s};                                     \
        cNH = (f32x4){bh2s, bh2s, bh2s, bh2s};                                     \
        _Pragma("unroll") for (int kt = 0; kt < KFX; ++kt) {                       \
            ax0 = __builtin_amdgcn_mfma_f32_16x16x32_f16(Sx[kt], bx[0][kt], ax0, 0, 0, 0); \
            ax1 = __builtin_amdgcn_mfma_f32_16x16x32_f16(Sx[kt], bx[1][kt], ax1, 0, 0, 0); \
            ax2 = __builtin_amdgcn_mfma_f32_16x16x32_f16(Sx[kt], bx[2][kt], ax2, 0, 0, 0); \
        }                                                                          \
        __builtin_amdgcn_s_setprio(1);                                             \
        _Pragma("unroll") for (int kt = 0; kt < 4; ++kt) {                         \
            ax0 = __builtin_amdgcn_mfma_f32_16x16x32_f16(ah[kt], bhh[0][kt], ax0, 0, 0, 0); \
            ax1 = __builtin_amdgcn_mfma_f32_16x16x32_f16(ah[kt], bhh[1][kt], ax1, 0, 0, 0); \
            cNH = __builtin_amdgcn_mfma_f32_16x16x32_f16(ah[kt], bhh[2][kt], cNH, 0, 0, 0); \
        }                                                                          \
        __builtin_amdgcn_s_setprio(0);                                             \
        LOADX(Sx, (tcur) + 2)                                                      \
    }

// Phase B: gates + h update + ds_write (+ global h1 store for producer).
#define GRU_B(tcur)                                                                \
    {                                                                              \
        float hn_[4];                                                              \
        _Pragma("unroll") for (int j = 0; j < 4; ++j) {                            \
            float rr = rcp_(1.f + exp2_(ax0[j]));                                  \
            float zz = rcp_(1.f + exp2_(ax1[j]));                                  \
            float v  = ax2[j] + rr * cNH[j];                                       \
            float nn = fmaf(2.f, rcp_(1.f + exp2_(v)), -1.f);                      \
            hn_[j] = nn + zz * (hreg[j] - nn);                                     \
            hreg[j] = hn_[j];                                                      \
        }                                                                          \
        char* hw = hs[((tcur) + 1) & 1];                                           \
        _Pragma("unroll") for (int j = 0; j < 4; ++j) {                            \
            int bb = rgrp * 4 + j;                                                 \
            *(_Float16*)(hw + swz256(bb, cw * 2)) = (_Float16)hn_[j];              \
            if constexpr (OUT_ALL) {                                               \
                ((_Float16*)hout)[((size_t)(b0 + bb) * T_SZ + (tcur)) * H_SZ + cw] \
                    = (_Float16)hn_[j];                                            \
            }                                                                      \
        }                                                                          \
        if (ROLE == 0 && (((tcur) & 7) == 7)) {                                    \
            asm volatile("s_waitcnt vmcnt(0)" ::: "memory");  /* pre-publish */    \
        }                                                                          \
    }

#define HBAR                                                                       \
    asm volatile("s_waitcnt lgkmcnt(0)" ::: "memory");                             \
    __builtin_amdgcn_s_barrier();                                                  \
    __builtin_amdgcn_sched_barrier(0);

// ROLE 0 = producer (layer 0), ROLE 1 = consumer (layer 1 + fused head)
template<int K_IN, bool OUT_ALL, int ROLE>
__device__ __forceinline__ void gru_body(const _Float16* __restrict__ xin,
                                         const float* __restrict__ W_ih,
                                         const float* __restrict__ W_hh,
                                         const float* __restrict__ b_ih,
                                         const float* __restrict__ b_hh,
                                         void* __restrict__ hout,
                                         const float* __restrict__ W_head,
                                         const float* __restrict__ b_head,
                                         float* __restrict__ out,
                                         int* __restrict__ prog,
                                         int grp, int gsel, char (*hs)[4096])
{
    constexpr int KFX  = K_IN / 32;
    constexpr int ROWB = K_IN * 2;     // fp16 row bytes

    const int tid  = threadIdx.x & 511;  // within group
    const int ln   = tid & 63;
    const int wv   = tid >> 6;           // wave 0..7 within group
    const int colg = ln & 15;
    const int rgrp = ln >> 4;
    const int b0   = grp * NB;
    const int cw   = wv * 16 + colg;     // hidden-unit column 0..127

    // ---- resident weight fragments (pre-scaled per gate) ----
    half8 bx[3][KFX];        // W_ih fp16
    half8 bhh[3][4];         // W_hh fp16
    const float gsc[3] = {SC_SIG, SC_SIG, SC_TANH};
    #pragma unroll
    for (int g = 0; g < 3; ++g) {
        int n0 = g * 128 + wv * 16;
        #pragma unroll
        for (int kt = 0; kt < KFX; ++kt)
            load_bfrag(W_ih, K_IN, n0, kt, ln, gsc[g], &bx[g][kt]);
        #pragma unroll
        for (int kt = 0; kt < 4; ++kt)
            load_bfrag(W_hh, H_SZ, n0, kt, ln, gsc[g], &bhh[g][kt]);
    }
    const float bs0  = SC_SIG  * (b_ih[cw] + b_hh[cw]);
    const float bs1  = SC_SIG  * (b_ih[128 + cw] + b_hh[128 + cw]);
    const float bi2s = SC_TANH * b_ih[256 + cw];
    const float bh2s = SC_TANH * b_hh[256 + cw];

    // consumer-only: resident head fragments (waves 0..5 cover P=96)
    half8 bph[4];
    float bhd = 0.f;
    if (ROLE == 1 && wv < 6) {
        #pragma unroll
        for (int kt = 0; kt < 4; ++kt)
            load_bfrag(W_head, H_SZ, wv * 16, kt, ln, 1.0f, &bph[kt]);
        bhd = b_head[cw];
    }

    if (tid < 256) *(float4*)(hs[0] + tid * 16) = make_float4(0.f, 0.f, 0.f, 0.f);
    float hreg[4] = {0.f, 0.f, 0.f, 0.f};

    // per-lane x row base: A-row = colg (batch), k-offset rgrp*8 elems (16B)
    const char* xlane = (const char*)xin
        + (size_t)(b0 + colg) * T_SZ * ROWB
        + rgrp * 16;

    int avail = 0;
    if (ROLE == 1) {
        while (avail < 4) {
            avail = __hip_atomic_load(prog, __ATOMIC_ACQUIRE, __HIP_MEMORY_SCOPE_AGENT);
            if (avail < 4) __builtin_amdgcn_s_sleep(8);
        }
    }

    half8 Ax[KFX], Bx2[KFX];
    LOADX(Ax, 0)
    LOADX(Bx2, 1)

    f32x4 ax0, ax1, ax2, cNH;
    __syncthreads();

    for (int t = 0; t < T_SZ; t += 2) {
        // ---- HP1: g0 A(t) | g1 B(t-1) ----
        if (ROLE == 0 && gsel == 0 && tid == 0 && t > 0 && (((t - 1) & 7) == 7))
            __hip_atomic_store(prog, t, __ATOMIC_RELEASE, __HIP_MEMORY_SCOPE_AGENT);
        if (gsel == 0) { GRU_A(Ax, t) }
        else if (t > 0) { GRU_B(t - 1) }
        HBAR
        // ---- HP2: g0 B(t) | g1 A(t) ----
        if (ROLE == 0 && gsel == 1 && tid == 0 && t > 0 && (((t - 1) & 7) == 7))
            __hip_atomic_store(prog, t, __ATOMIC_RELEASE, __HIP_MEMORY_SCOPE_AGENT);
        if (gsel == 0) { GRU_B(t) }
        else           { GRU_A(Ax, t) }
        HBAR
        // ---- HP3: g0 A(t+1) | g1 B(t) ----
        if (gsel == 0) { GRU_A(Bx2, t + 1) }
        else           { GRU_B(t) }
        HBAR
        // ---- HP4: g0 B(t+1) | g1 A(t+1) ----
        if (gsel == 0) { GRU_B(t + 1) }
        else           { GRU_A(Bx2, t + 1) }
        HBAR
    }
    // tail: g1 still owes B(T-1)
    if (gsel == 1) { GRU_B(T_SZ - 1) }
    __syncthreads();
    if (ROLE == 0 && tid == 0)
        __hip_atomic_store(prog, T_SZ, __ATOMIC_RELEASE, __HIP_MEMORY_SCOPE_AGENT);

    // ---- fused head (consumer only): out = h(T) @ W_head^T + b_head ----
    if (ROLE == 1 && wv < 6) {
        half8 ahf[4];
        #pragma unroll
        for (int kt = 0; kt < 4; ++kt)
            ahf[kt] = *(const half8*)(hs[0] + swz256(colg, kt * 64 + rgrp * 16));
        f32x4 acc = {bhd, bhd, bhd, bhd};
        #pragma unroll
        for (int kt = 0; kt < 4; ++kt)
            acc = __builtin_amdgcn_mfma_f32_16x16x32_f16(ahf[kt], bph[kt], acc, 0, 0, 0);
        #pragma unroll
        for (int j = 0; j < 4; ++j)
            out[(size_t)(b0 + rgrp * 4 + j) * P_SZ + cw] = acc[j];
    }
}

__global__ __launch_bounds__(1024)
void gru_fused(const _Float16* __restrict__ xh,  // (B,T,64) fp16
               _Float16* __restrict__ h1,        // (B,T,128) fp16
               const float* __restrict__ W_ih0, const float* __restrict__ W_hh0,
               const float* __restrict__ b_ih0, const float* __restrict__ b_hh0,
               const float* __restrict__ W_ih1, const float* __restrict__ W_hh1,
               const float* __restrict__ b_ih1, const float* __restrict__ b_hh1,
               const float* __restrict__ W_head, const float* __restrict__ b_head,
               float* __restrict__ out,          // (B,96) f32
               int* __restrict__ prog)
{
    __shared__ __align__(16) char hs[2][2][4096];   // [group][buf]
    const int role = blockIdx.x >> 4;   // grid = 32: 0-15 prod, 16-31 cons
    const int gblk = blockIdx.x & 15;
    const int gsel = threadIdx.x >> 9;  // 0 or 1
    const int grp  = gblk * 2 + gsel;
    if (role == 0)
        gru_body<E_SZ, true, 0>(xh, W_ih0, W_hh0, b_ih0, b_hh0, h1,
                                W_head, b_head, out, prog + grp, grp, gsel, hs[gsel]);
    else
        gru_body<H_SZ, false, 1>(h1, W_ih1, W_hh1, b_ih1, b_hh1, nullptr,
                                 W_head, b_head, out, prog + grp, grp, gsel, hs[gsel]);
}

__global__ __launch_bounds__(256)
void cvt_f32_f16(const float* __restrict__ in, _Float16* __restrict__ out, int n8)
{
    int i = blockIdx.x * 256 + threadIdx.x;
    if (i >= n8) return;
    const float4* p = (const float4*)in + (size_t)i * 2;
    float4 a = p[0];
    float4 b = p[1];
    half8 h;
    h[0] = (_Float16)a.x; h[1] = (_Float16)a.y; h[2] = (_Float16)a.z; h[3] = (_Float16)a.w;
    h[4] = (_Float16)b.x; h[5] = (_Float16)b.y; h[6] = (_Float16)b.z; h[7] = (_Float16)b.w;
    ((half8*)out)[i] = h;
}

extern "C" void kernel_launch(void* const* d_in, const int* in_sizes, int n_in,
                              void* d_out, int out_size, void* d_ws, size_t ws_size,
                              hipStream_t stream)
{
    const float* x      = (const float*)d_in[0];
    const float* W_ih0  = (const float*)d_in[1];
    const float* W_hh0  = (const float*)d_in[2];
    const float* b_ih0  = (const float*)d_in[3];
    const float* b_hh0  = (const float*)d_in[4];
    const float* W_ih1  = (const float*)d_in[5];
    const float* W_hh1  = (const float*)d_in[6];
    const float* b_ih1  = (const float*)d_in[7];
    const float* b_hh1  = (const float*)d_in[8];
    const float* W_head = (const float*)d_in[9];
    const float* b_head = (const float*)d_in[10];
    float* out = (float*)d_out;

    char* ws = (char*)d_ws;
    _Float16* h1  = (_Float16*)ws;                              // 64 MiB (B,T,128) fp16
    _Float16* xh  = (_Float16*)(ws + (64u << 20));              // 32 MiB (B,T,64)  fp16
    int*      prg = (int*)     (ws + (96u << 20));

    hipMemsetAsync(prg, 0, NGRP * sizeof(int), stream);
    cvt_f32_f16<<<(B_SZ * T_SZ * E_SZ / 8 + 255) / 256, 256, 0, stream>>>(x, xh, B_SZ * T_SZ * E_SZ / 8);
    gru_fused<<<2 * (NGRP / 2), 1024, 0, stream>>>(xh, h1,
                                                   W_ih0, W_hh0, b_ih0, b_hh0,
                                                   W_ih1, W_hh1, b_ih1, b_hh1,
                                                   W_head, b_head, out, prg);
}

// Round 11
// 4318.175 us; speedup vs baseline: 1.0207x; 1.0207x over previous
//
#include <hip/hip_runtime.h>

// GRU_10746008175428 round 11: de-phased dual-group blocks, register-fixed.
// B=512 T=512 E=64 H=128 P=96.
// 32 blocks x 1024 thr (16 waves, 4/SIMD, ONE workgroup per CU via
// __launch_bounds__(1024,4) -> 128-VGPR cap; r10's bare (1024) let the
// compiler target 2 WG/CU = 64-VGPR cap and spilled all weights).
// Each block = TWO batch groups (waves 0-7 = g0, 8-15 = g1) offset by half
// a step: while one group runs phase-A {ds_read h, x-MFMA, hh-MFMA, x
// prefetch} (LDS+MFMA pipes), the other runs phase-B {gates, ds_write,
// h1 store} (trans+VALU pipes). Pipes overlap across groups instead of
// block-serializing per phase.
// Blocks 0-15 producers (layer 0), 16-31 consumers (layer 1 + fused head).
// W_head fragments now loaded in the EPILOGUE (r9/r10 held them live
// through the whole loop: 17 wasted VGPRs under the cap).
// Per-group math identical to r9/r10 -> absmax invariant (9.77e-4).

#define B_SZ 512
#define T_SZ 512
#define E_SZ 64
#define H_SZ 128
#define P_SZ 96
#define NB   16
#define NGRP (B_SZ / NB)          // 32 groups
#define SC_SIG  (-1.44269504f)   // -log2(e)
#define SC_TANH (-2.88539008f)   // -2*log2(e)

typedef _Float16 half8 __attribute__((ext_vector_type(8)));
typedef float    f32x4 __attribute__((ext_vector_type(4)));

__device__ __forceinline__ float exp2_(float x) {
#if __has_builtin(__builtin_amdgcn_exp2f)
    return __builtin_amdgcn_exp2f(x);
#else
    return exp2f(x);
#endif
}
__device__ __forceinline__ float rcp_(float x) {
#if __has_builtin(__builtin_amdgcn_rcpf)
    return __builtin_amdgcn_rcpf(x);
#else
    return 1.0f / x;
#endif
}

// XOR-swizzled byte offset in a [rows][256B] LDS tile
__device__ __forceinline__ int swz256(int row, int byte) {
    return row * 256 + (byte ^ ((row & 7) << 4));
}

// One B-fragment (16 cols x 32 k) from fp32 weight matrix W, pre-scaled.
__device__ __forceinline__ void load_bfrag(const float* __restrict__ W, int ldk,
                                           int n0, int kt, int ln, float scale,
                                           half8* hi) {
    int n = n0 + (ln & 15);
    int k = kt * 32 + (ln >> 4) * 8;
    const float* p = W + (size_t)n * ldk + k;
    float4 a = *(const float4*)p;
    float4 b = *(const float4*)(p + 4);
    float v[8] = {a.x, a.y, a.z, a.w, b.x, b.y, b.z, b.w};
    half8 h;
    #pragma unroll
    for (int j = 0; j < 8; ++j)
        h[j] = (_Float16)(v[j] * scale);
    *hi = h;
}

#define LOADX(Sx, tt)                                                              \
    if ((tt) < T_SZ) {                                                             \
        _Pragma("unroll") for (int kt = 0; kt < KFX; ++kt)                         \
            Sx[kt] = *(const half8*)(xlane + (size_t)(tt) * ROWB + kt * 64);       \
    }

// Phase A: all MFMAs for step tcur + x prefetch (tcur+2). Leaves ax0/ax1
// (r,z pre-acts), ax2 (n x-part), cNH (n hh-part) live for phase B.
#define GRU_A(Sx, tcur)                                                            \
    {                                                                              \
        if (ROLE == 1 && (((tcur) & 1) == 0) && avail < T_SZ) {                    \
            const int need = ((tcur) + 4 < T_SZ) ? (tcur) + 4 : T_SZ;              \
            while (avail < need) {                                                 \
                avail = __hip_atomic_load(prog, __ATOMIC_ACQUIRE,                  \
                                          __HIP_MEMORY_SCOPE_AGENT);               \
                if (avail < need) __builtin_amdgcn_s_sleep(8);                     \
            }                                                                      \
        }                                                                          \
        const char* hb = hs[(tcur) & 1];                                           \
        half8 ah[4];                                                               \
        _Pragma("unroll") for (int kt = 0; kt < 4; ++kt)                           \
            ah[kt] = *(const half8*)(hb + swz256(colg, kt * 64 + rgrp * 16));      \
        ax0 = (f32x4){bs0, bs0, bs0, bs0};                                         \
        ax1 = (f32x4){bs1, bs1, bs1, bs1};                                         \
        ax2 = (f32x4){bi2s, bi2s, bi2s, bi2s};                                     \
        cNH = (f32x4){bh2s, bh2s, bh2s, bh2s};                                     \
        _Pragma("unroll") for (int kt = 0; kt < KFX; ++kt) {                       \
            ax0 = __builtin_amdgcn_mfma_f32_16x16x32_f16(Sx[kt], bx[0][kt], ax0, 0, 0, 0); \
            ax1 = __builtin_amdgcn_mfma_f32_16x16x32_f16(Sx[kt], bx[1][kt], ax1, 0, 0, 0); \
            ax2 = __builtin_amdgcn_mfma_f32_16x16x32_f16(Sx[kt], bx[2][kt], ax2, 0, 0, 0); \
        }                                                                          \
        __builtin_amdgcn_s_setprio(1);                                             \
        _Pragma("unroll") for (int kt = 0; kt < 4; ++kt) {                         \
            ax0 = __builtin_amdgcn_mfma_f32_16x16x32_f16(ah[kt], bhh[0][kt], ax0, 0, 0, 0); \
            ax1 = __builtin_amdgcn_mfma_f32_16x16x32_f16(ah[kt], bhh[1][kt], ax1, 0, 0, 0); \
            cNH = __builtin_amdgcn_mfma_f32_16x16x32_f16(ah[kt], bhh[2][kt], cNH, 0, 0, 0); \
        }                                                                          \
        __builtin_amdgcn_s_setprio(0);                                             \
        LOADX(Sx, (tcur) + 2)                                                      \
    }

// Phase B: gates + h update + ds_write (+ global h1 store for producer).
#define GRU_B(tcur)                                                                \
    {                                                                              \
        float hn_[4];                                                              \
        _Pragma("unroll") for (int j = 0; j < 4; ++j) {                            \
            float rr = rcp_(1.f + exp2_(ax0[j]));                                  \
            float zz = rcp_(1.f + exp2_(ax1[j]));                                  \
            float v  = ax2[j] + rr * cNH[j];                                       \
            float nn = fmaf(2.f, rcp_(1.f + exp2_(v)), -1.f);                      \
            hn_[j] = nn + zz * (hreg[j] - nn);                                     \
            hreg[j] = hn_[j];                                                      \
        }                                                                          \
        char* hw = hs[((tcur) + 1) & 1];                                           \
        _Pragma("unroll") for (int j = 0; j < 4; ++j) {                            \
            int bb = rgrp * 4 + j;                                                 \
            *(_Float16*)(hw + swz256(bb, cw * 2)) = (_Float16)hn_[j];              \
            if constexpr (OUT_ALL) {                                               \
                ((_Float16*)hout)[((size_t)(b0 + bb) * T_SZ + (tcur)) * H_SZ + cw] \
                    = (_Float16)hn_[j];                                            \
            }                                                                      \
        }                                                                          \
        if (ROLE == 0 && (((tcur) & 7) == 7)) {                                    \
            asm volatile("s_waitcnt vmcnt(0)" ::: "memory");  /* pre-publish */    \
        }                                                                          \
    }

#define HBAR                                                                       \
    asm volatile("s_waitcnt lgkmcnt(0)" ::: "memory");                             \
    __builtin_amdgcn_s_barrier();                                                  \
    __builtin_amdgcn_sched_barrier(0);

// ROLE 0 = producer (layer 0), ROLE 1 = consumer (layer 1 + fused head)
template<int K_IN, bool OUT_ALL, int ROLE>
__device__ __forceinline__ void gru_body(const _Float16* __restrict__ xin,
                                         const float* __restrict__ W_ih,
                                         const float* __restrict__ W_hh,
                                         const float* __restrict__ b_ih,
                                         const float* __restrict__ b_hh,
                                         void* __restrict__ hout,
                                         const float* __restrict__ W_head,
                                         const float* __restrict__ b_head,
                                         float* __restrict__ out,
                                         int* __restrict__ prog,
                                         int grp, int gsel, char (*hs)[4096])
{
    constexpr int KFX  = K_IN / 32;
    constexpr int ROWB = K_IN * 2;     // fp16 row bytes

    const int tid  = threadIdx.x & 511;  // within group
    const int ln   = tid & 63;
    const int wv   = tid >> 6;           // wave 0..7 within group
    const int colg = ln & 15;
    const int rgrp = ln >> 4;
    const int b0   = grp * NB;
    const int cw   = wv * 16 + colg;     // hidden-unit column 0..127

    // ---- resident weight fragments (pre-scaled per gate) ----
    half8 bx[3][KFX];        // W_ih fp16
    half8 bhh[3][4];         // W_hh fp16
    const float gsc[3] = {SC_SIG, SC_SIG, SC_TANH};
    #pragma unroll
    for (int g = 0; g < 3; ++g) {
        int n0 = g * 128 + wv * 16;
        #pragma unroll
        for (int kt = 0; kt < KFX; ++kt)
            load_bfrag(W_ih, K_IN, n0, kt, ln, gsc[g], &bx[g][kt]);
        #pragma unroll
        for (int kt = 0; kt < 4; ++kt)
            load_bfrag(W_hh, H_SZ, n0, kt, ln, gsc[g], &bhh[g][kt]);
    }
    const float bs0  = SC_SIG  * (b_ih[cw] + b_hh[cw]);
    const float bs1  = SC_SIG  * (b_ih[128 + cw] + b_hh[128 + cw]);
    const float bi2s = SC_TANH * b_ih[256 + cw];
    const float bh2s = SC_TANH * b_hh[256 + cw];

    if (tid < 256) *(float4*)(hs[0] + tid * 16) = make_float4(0.f, 0.f, 0.f, 0.f);
    float hreg[4] = {0.f, 0.f, 0.f, 0.f};

    // per-lane x row base: A-row = colg (batch), k-offset rgrp*8 elems (16B)
    const char* xlane = (const char*)xin
        + (size_t)(b0 + colg) * T_SZ * ROWB
        + rgrp * 16;

    int avail = 0;
    if (ROLE == 1) {
        while (avail < 4) {
            avail = __hip_atomic_load(prog, __ATOMIC_ACQUIRE, __HIP_MEMORY_SCOPE_AGENT);
            if (avail < 4) __builtin_amdgcn_s_sleep(8);
        }
    }

    half8 Ax[KFX], Bx2[KFX];
    LOADX(Ax, 0)
    LOADX(Bx2, 1)

    f32x4 ax0, ax1, ax2, cNH;
    __syncthreads();

    for (int t = 0; t < T_SZ; t += 2) {
        // ---- HP1: g0 A(t) | g1 B(t-1) ----
        if (ROLE == 0 && gsel == 0 && tid == 0 && t > 0 && (((t - 1) & 7) == 7))
            __hip_atomic_store(prog, t, __ATOMIC_RELEASE, __HIP_MEMORY_SCOPE_AGENT);
        if (gsel == 0) { GRU_A(Ax, t) }
        else if (t > 0) { GRU_B(t - 1) }
        HBAR
        // ---- HP2: g0 B(t) | g1 A(t) ----
        if (ROLE == 0 && gsel == 1 && tid == 0 && t > 0 && (((t - 1) & 7) == 7))
            __hip_atomic_store(prog, t, __ATOMIC_RELEASE, __HIP_MEMORY_SCOPE_AGENT);
        if (gsel == 0) { GRU_B(t) }
        else           { GRU_A(Ax, t) }
        HBAR
        // ---- HP3: g0 A(t+1) | g1 B(t) ----
        if (gsel == 0) { GRU_A(Bx2, t + 1) }
        else           { GRU_B(t) }
        HBAR
        // ---- HP4: g0 B(t+1) | g1 A(t+1) ----
        if (gsel == 0) { GRU_B(t + 1) }
        else           { GRU_A(Bx2, t + 1) }
        HBAR
    }
    // tail: g1 still owes B(T-1)
    if (gsel == 1) { GRU_B(T_SZ - 1) }
    __syncthreads();
    if (ROLE == 0 && tid == 0)
        __hip_atomic_store(prog, T_SZ, __ATOMIC_RELEASE, __HIP_MEMORY_SCOPE_AGENT);

    // ---- fused head (consumer only): out = h(T) @ W_head^T + b_head ----
    // W_head fragments loaded HERE (epilogue) so they are not live in the loop.
    if (ROLE == 1 && wv < 6) {
        half8 bph[4];
        #pragma unroll
        for (int kt = 0; kt < 4; ++kt)
            load_bfrag(W_head, H_SZ, wv * 16, kt, ln, 1.0f, &bph[kt]);
        const float bhd = b_head[cw];
        half8 ahf[4];
        #pragma unroll
        for (int kt = 0; kt < 4; ++kt)
            ahf[kt] = *(const half8*)(hs[0] + swz256(colg, kt * 64 + rgrp * 16));
        f32x4 acc = {bhd, bhd, bhd, bhd};
        #pragma unroll
        for (int kt = 0; kt < 4; ++kt)
            acc = __builtin_amdgcn_mfma_f32_16x16x32_f16(ahf[kt], bph[kt], acc, 0, 0, 0);
        #pragma unroll
        for (int j = 0; j < 4; ++j)
            out[(size_t)(b0 + rgrp * 4 + j) * P_SZ + cw] = acc[j];
    }
}

__global__ __launch_bounds__(1024, 4)   // 4 waves/EU = ONE 16-wave WG/CU -> 128-VGPR cap
void gru_fused(const _Float16* __restrict__ xh,  // (B,T,64) fp16
               _Float16* __restrict__ h1,        // (B,T,128) fp16
               const float* __restrict__ W_ih0, const float* __restrict__ W_hh0,
               const float* __restrict__ b_ih0, const float* __restrict__ b_hh0,
               const float* __restrict__ W_ih1, const float* __restrict__ W_hh1,
               const float* __restrict__ b_ih1, const float* __restrict__ b_hh1,
               const float* __restrict__ W_head, const float* __restrict__ b_head,
               float* __restrict__ out,          // (B,96) f32
               int* __restrict__ prog)
{
    __shared__ __align__(16) char hs[2][2][4096];   // [group][buf]
    const int role = blockIdx.x >> 4;   // grid = 32: 0-15 prod, 16-31 cons
    const int gblk = blockIdx.x & 15;
    const int gsel = threadIdx.x >> 9;  // 0 or 1
    const int grp  = gblk * 2 + gsel;
    if (role == 0)
        gru_body<E_SZ, true, 0>(xh, W_ih0, W_hh0, b_ih0, b_hh0, h1,
                                W_head, b_head, out, prog + grp, grp, gsel, hs[gsel]);
    else
        gru_body<H_SZ, false, 1>(h1, W_ih1, W_hh1, b_ih1, b_hh1, nullptr,
                                 W_head, b_head, out, prog + grp, grp, gsel, hs[gsel]);
}

__global__ __launch_bounds__(256)
void cvt_f32_f16(const float* __restrict__ in, _Float16* __restrict__ out, int n8)
{
    int i = blockIdx.x * 256 + threadIdx.x;
    if (i >= n8) return;
    const float4* p = (const float4*)in + (size_t)i * 2;
    float4 a = p[0];
    float4 b = p[1];
    half8 h;
    h[0] = (_Float16)a.x; h[1] = (_Float16)a.y; h[2] = (_Float16)a.z; h[3] = (_Float16)a.w;
    h[4] = (_Float16)b.x; h[5] = (_Float16)b.y; h[6] = (_Float16)b.z; h[7] = (_Float16)b.w;
    ((half8*)out)[i] = h;
}

extern "C" void kernel_launch(void* const* d_in, const int* in_sizes, int n_in,
                              void* d_out, int out_size, void* d_ws, size_t ws_size,
                              hipStream_t stream)
{
    const float* x      = (const float*)d_in[0];
    const float* W_ih0  = (const float*)d_in[1];
    const float* W_hh0  = (const float*)d_in[2];
    const float* b_ih0  = (const float*)d_in[3];
    const float* b_hh0  = (const float*)d_in[4];
    const float* W_ih1  = (const float*)d_in[5];
    const float* W_hh1  = (const float*)d_in[6];
    const float* b_ih1  = (const float*)d_in[7];
    const float* b_hh1  = (const float*)d_in[8];
    const float* W_head = (const float*)d_in[9];
    const float* b_head = (const float*)d_in[10];
    float* out = (float*)d_out;

    char* ws = (char*)d_ws;
    _Float16* h1  = (_Float16*)ws;                              // 64 MiB (B,T,128) fp16
    _Float16* xh  = (_Float16*)(ws + (64u << 20));              // 32 MiB (B,T,64)  fp16
    int*      prg = (int*)     (ws + (96u << 20));

    hipMemsetAsync(prg, 0, NGRP * sizeof(int), stream);
    cvt_f32_f16<<<(B_SZ * T_SZ * E_SZ / 8 + 255) / 256, 256, 0, stream>>>(x, xh, B_SZ * T_SZ * E_SZ / 8);
    gru_fused<<<2 * (NGRP / 2), 1024, 0, stream>>>(xh, h1,
                                                   W_ih0, W_hh0, b_ih0, b_hh0,
                                                   W_ih1, W_hh1, b_ih1, b_hh1,
                                                   W_head, b_head, out, prg);
}

// Round 12
// 972.192 us; speedup vs baseline: 4.5337x; 4.4417x over previous
//
#include <hip/hip_runtime.h>

// GRU_10746008175428 round 12: dual-group ILP blocks (de-phase r10/r11 idea,
// but inside 512-thread blocks where the register cap is 256, not 64).
// B=512 T=512 E=64 H=128 P=96.
// 32 blocks x 512 thr (8 waves, 2/SIMD, 1 WG/CU via __launch_bounds__(512,2)).
// Each block owns TWO batch groups (A = 2*gblk, B = 2*gblk+1); weights are
// SHARED (same fragments). Per barrier interval each wave runs:
//   A-MFMA -> B-MFMA -> A-gates -> B-gates -> one lgkm barrier.
// Groups are independent -> B's MFMAs overlap A's trans/VALU gate chain
// (separate pipes), and one barrier covers two group-steps.
// Blocks 0-15 producers (layer 0), 16-31 consumers (layer 1 + fused head).
// One prog counter per block pair, publish every 8 steps.
// Per-group math identical to r9 -> absmax invariant (9.77e-4).

#define B_SZ 512
#define T_SZ 512
#define E_SZ 64
#define H_SZ 128
#define P_SZ 96
#define NB   16
#define NGRP (B_SZ / NB)          // 32 groups
#define NBLK 16                   // block pairs
#define SC_SIG  (-1.44269504f)   // -log2(e)
#define SC_TANH (-2.88539008f)   // -2*log2(e)

typedef _Float16 half8 __attribute__((ext_vector_type(8)));
typedef float    f32x4 __attribute__((ext_vector_type(4)));

__device__ __forceinline__ float exp2_(float x) {
#if __has_builtin(__builtin_amdgcn_exp2f)
    return __builtin_amdgcn_exp2f(x);
#else
    return exp2f(x);
#endif
}
__device__ __forceinline__ float rcp_(float x) {
#if __has_builtin(__builtin_amdgcn_rcpf)
    return __builtin_amdgcn_rcpf(x);
#else
    return 1.0f / x;
#endif
}

// XOR-swizzled byte offset in a [rows][256B] LDS tile
__device__ __forceinline__ int swz256(int row, int byte) {
    return row * 256 + (byte ^ ((row & 7) << 4));
}

// One B-fragment (16 cols x 32 k) from fp32 weight matrix W, pre-scaled.
__device__ __forceinline__ void load_bfrag(const float* __restrict__ W, int ldk,
                                           int n0, int kt, int ln, float scale,
                                           half8* hi) {
    int n = n0 + (ln & 15);
    int k = kt * 32 + (ln >> 4) * 8;
    const float* p = W + (size_t)n * ldk + k;
    float4 a = *(const float4*)p;
    float4 b = *(const float4*)(p + 4);
    float v[8] = {a.x, a.y, a.z, a.w, b.x, b.y, b.z, b.w};
    half8 h;
    #pragma unroll
    for (int j = 0; j < 8; ++j)
        h[j] = (_Float16)(v[j] * scale);
    *hi = h;
}

#define LOADX(Sx, XL, tt)                                                          \
    if ((tt) < T_SZ) {                                                             \
        _Pragma("unroll") for (int kt = 0; kt < KFX; ++kt)                         \
            Sx[kt] = *(const half8*)((XL) + (size_t)(tt) * ROWB + kt * 64);        \
    }

// MFMA half of one group-step: ds_read h, x-MFMA + hh-MFMA into A0/A1/A2/CN,
// then reload Sx with x(tcur+2). Leaves accumulators live for GRU_FIN.
#define GRU_MFMA(Sx, XL, HS, A0, A1, A2, CN, tcur)                                 \
    {                                                                              \
        const char* hb = (HS)[(tcur) & 1];                                         \
        half8 ah[4];                                                               \
        _Pragma("unroll") for (int kt = 0; kt < 4; ++kt)                           \
            ah[kt] = *(const half8*)(hb + swz256(colg, kt * 64 + rgrp * 16));      \
        A0 = (f32x4){bs0, bs0, bs0, bs0};                                          \
        A1 = (f32x4){bs1, bs1, bs1, bs1};                                          \
        A2 = (f32x4){bi2s, bi2s, bi2s, bi2s};                                      \
        CN = (f32x4){bh2s, bh2s, bh2s, bh2s};                                      \
        _Pragma("unroll") for (int kt = 0; kt < KFX; ++kt) {                       \
            A0 = __builtin_amdgcn_mfma_f32_16x16x32_f16(Sx[kt], bx[0][kt], A0, 0, 0, 0); \
            A1 = __builtin_amdgcn_mfma_f32_16x16x32_f16(Sx[kt], bx[1][kt], A1, 0, 0, 0); \
            A2 = __builtin_amdgcn_mfma_f32_16x16x32_f16(Sx[kt], bx[2][kt], A2, 0, 0, 0); \
        }                                                                          \
        _Pragma("unroll") for (int kt = 0; kt < 4; ++kt) {                         \
            A0 = __builtin_amdgcn_mfma_f32_16x16x32_f16(ah[kt], bhh[0][kt], A0, 0, 0, 0); \
            A1 = __builtin_amdgcn_mfma_f32_16x16x32_f16(ah[kt], bhh[1][kt], A1, 0, 0, 0); \
            CN = __builtin_amdgcn_mfma_f32_16x16x32_f16(ah[kt], bhh[2][kt], CN, 0, 0, 0); \
        }                                                                          \
        LOADX(Sx, XL, (tcur) + 2)                                                  \
    }

// Gate half of one group-step: nonlinearities, h update, ds_write (+ global
// h1 store for producer).
#define GRU_FIN(HS, HREG, A0, A1, A2, CN, BOFF, tcur)                              \
    {                                                                              \
        float hn_[4];                                                              \
        _Pragma("unroll") for (int j = 0; j < 4; ++j) {                            \
            float rr = rcp_(1.f + exp2_(A0[j]));                                   \
            float zz = rcp_(1.f + exp2_(A1[j]));                                   \
            float v  = A2[j] + rr * CN[j];                                         \
            float nn = fmaf(2.f, rcp_(1.f + exp2_(v)), -1.f);                      \
            hn_[j] = nn + zz * (HREG[j] - nn);                                     \
            HREG[j] = hn_[j];                                                      \
        }                                                                          \
        char* hw = (HS)[((tcur) + 1) & 1];                                         \
        _Pragma("unroll") for (int j = 0; j < 4; ++j) {                            \
            int bb = rgrp * 4 + j;                                                 \
            *(_Float16*)(hw + swz256(bb, cw * 2)) = (_Float16)hn_[j];              \
            if constexpr (OUT_ALL) {                                               \
                ((_Float16*)hout)[((size_t)((BOFF) + bb) * T_SZ + (tcur)) * H_SZ + cw] \
                    = (_Float16)hn_[j];                                            \
            }                                                                      \
        }                                                                          \
    }

#define HBAR                                                                       \
    asm volatile("s_waitcnt lgkmcnt(0)" ::: "memory");                             \
    __builtin_amdgcn_s_barrier();                                                  \
    __builtin_amdgcn_sched_barrier(0);

// ROLE 0 = producer (layer 0), ROLE 1 = consumer (layer 1 + fused head)
template<int K_IN, bool OUT_ALL, int ROLE>
__device__ __forceinline__ void gru_body(const _Float16* __restrict__ xin,
                                         const float* __restrict__ W_ih,
                                         const float* __restrict__ W_hh,
                                         const float* __restrict__ b_ih,
                                         const float* __restrict__ b_hh,
                                         void* __restrict__ hout,
                                         const float* __restrict__ W_head,
                                         const float* __restrict__ b_head,
                                         float* __restrict__ out,
                                         int* __restrict__ prog,
                                         int gblk, char (*hsA)[4096], char (*hsB)[4096])
{
    constexpr int KFX  = K_IN / 32;
    constexpr int ROWB = K_IN * 2;     // fp16 row bytes

    const int tid  = threadIdx.x;
    const int ln   = tid & 63;
    const int wv   = tid >> 6;        // wave 0..7 -> col tile
    const int colg = ln & 15;
    const int rgrp = ln >> 4;
    const int b0A  = gblk * 2 * NB;
    const int b0B  = b0A + NB;
    const int cw   = wv * 16 + colg;  // hidden-unit column 0..127

    // ---- resident weight fragments (pre-scaled per gate, SHARED by groups) ----
    half8 bx[3][KFX];        // W_ih fp16
    half8 bhh[3][4];         // W_hh fp16
    const float gsc[3] = {SC_SIG, SC_SIG, SC_TANH};
    #pragma unroll
    for (int g = 0; g < 3; ++g) {
        int n0 = g * 128 + wv * 16;
        #pragma unroll
        for (int kt = 0; kt < KFX; ++kt)
            load_bfrag(W_ih, K_IN, n0, kt, ln, gsc[g], &bx[g][kt]);
        #pragma unroll
        for (int kt = 0; kt < 4; ++kt)
            load_bfrag(W_hh, H_SZ, n0, kt, ln, gsc[g], &bhh[g][kt]);
    }
    const float bs0  = SC_SIG  * (b_ih[cw] + b_hh[cw]);
    const float bs1  = SC_SIG  * (b_ih[128 + cw] + b_hh[128 + cw]);
    const float bi2s = SC_TANH * b_ih[256 + cw];
    const float bh2s = SC_TANH * b_hh[256 + cw];

    if (tid < 256) {
        *(float4*)(hsA[0] + tid * 16) = make_float4(0.f, 0.f, 0.f, 0.f);
        *(float4*)(hsB[0] + tid * 16) = make_float4(0.f, 0.f, 0.f, 0.f);
    }
    float hregA[4] = {0.f, 0.f, 0.f, 0.f};
    float hregB[4] = {0.f, 0.f, 0.f, 0.f};

    // per-lane x row bases: A-row = colg (batch), k-offset rgrp*8 elems (16B)
    const char* xlaneA = (const char*)xin
        + (size_t)(b0A + colg) * T_SZ * ROWB + rgrp * 16;
    const char* xlaneB = (const char*)xin
        + (size_t)(b0B + colg) * T_SZ * ROWB + rgrp * 16;

    int avail = 0;
    if (ROLE == 1) {
        while (avail < 4) {
            avail = __hip_atomic_load(prog, __ATOMIC_ACQUIRE, __HIP_MEMORY_SCOPE_AGENT);
            if (avail < 4) __builtin_amdgcn_s_sleep(8);
        }
    }

    half8 AxA[KFX], BxA[KFX], AxB[KFX], BxB[KFX];
    LOADX(AxA, xlaneA, 0)
    LOADX(BxA, xlaneA, 1)
    LOADX(AxB, xlaneB, 0)
    LOADX(BxB, xlaneB, 1)

    f32x4 aA0, aA1, aA2, cA, aB0, aB1, aB2, cB;
    __syncthreads();

    for (int t = 0; t < T_SZ; t += 2) {
        if (ROLE == 1 && avail < T_SZ) {
            const int need = (t + 4 < T_SZ) ? t + 4 : T_SZ;
            while (avail < need) {
                avail = __hip_atomic_load(prog, __ATOMIC_ACQUIRE, __HIP_MEMORY_SCOPE_AGENT);
                if (avail < need) __builtin_amdgcn_s_sleep(8);
            }
        }
        // ---- interval 1: step t for both groups, one barrier ----
        GRU_MFMA(AxA, xlaneA, hsA, aA0, aA1, aA2, cA, t)
        GRU_MFMA(AxB, xlaneB, hsB, aB0, aB1, aB2, cB, t)
        GRU_FIN(hsA, hregA, aA0, aA1, aA2, cA, b0A, t)
        GRU_FIN(hsB, hregB, aB0, aB1, aB2, cB, b0B, t)
        HBAR
        // ---- interval 2: step t+1 for both groups, one barrier ----
        GRU_MFMA(BxA, xlaneA, hsA, aA0, aA1, aA2, cA, t + 1)
        GRU_MFMA(BxB, xlaneB, hsB, aB0, aB1, aB2, cB, t + 1)
        GRU_FIN(hsA, hregA, aA0, aA1, aA2, cA, b0A, t + 1)
        GRU_FIN(hsB, hregB, aB0, aB1, aB2, cB, b0B, t + 1)
        HBAR
        if (ROLE == 0 && (t & 7) == 6) {
            // publish progress: own stores drained -> block barrier -> release
            asm volatile("s_waitcnt vmcnt(0)" ::: "memory");
            __builtin_amdgcn_s_barrier();
            if (tid == 0)
                __hip_atomic_store(prog, t + 2, __ATOMIC_RELEASE, __HIP_MEMORY_SCOPE_AGENT);
        }
    }

    // ---- fused head (consumer only): out = h(T) @ W_head^T + b_head ----
    // hsA[0]/hsB[0] hold h(T) in A-frag layout (T even, last barrier passed).
    if (ROLE == 1 && wv < 6) {
        half8 bph[4];
        #pragma unroll
        for (int kt = 0; kt < 4; ++kt)
            load_bfrag(W_head, H_SZ, wv * 16, kt, ln, 1.0f, &bph[kt]);
        const float bhd = b_head[cw];
        #pragma unroll
        for (int g = 0; g < 2; ++g) {
            const char* hsrc = g ? hsB[0] : hsA[0];
            const int   boff = g ? b0B : b0A;
            half8 ahf[4];
            #pragma unroll
            for (int kt = 0; kt < 4; ++kt)
                ahf[kt] = *(const half8*)(hsrc + swz256(colg, kt * 64 + rgrp * 16));
            f32x4 acc = {bhd, bhd, bhd, bhd};
            #pragma unroll
            for (int kt = 0; kt < 4; ++kt)
                acc = __builtin_amdgcn_mfma_f32_16x16x32_f16(ahf[kt], bph[kt], acc, 0, 0, 0);
            #pragma unroll
            for (int j = 0; j < 4; ++j)
                out[(size_t)(boff + rgrp * 4 + j) * P_SZ + cw] = acc[j];
        }
    }
}

__global__ __launch_bounds__(512, 2)   // 2 waves/EU -> 1 WG/CU -> 256-VGPR cap
void gru_fused(const _Float16* __restrict__ xh,  // (B,T,64) fp16
               _Float16* __restrict__ h1,        // (B,T,128) fp16
               const float* __restrict__ W_ih0, const float* __restrict__ W_hh0,
               const float* __restrict__ b_ih0, const float* __restrict__ b_hh0,
               const float* __restrict__ W_ih1, const float* __restrict__ W_hh1,
               const float* __restrict__ b_ih1, const float* __restrict__ b_hh1,
               const float* __restrict__ W_head, const float* __restrict__ b_head,
               float* __restrict__ out,          // (B,96) f32
               int* __restrict__ prog)
{
    __shared__ __align__(16) char hs[2][2][4096];   // [group][buf]
    const int role = blockIdx.x >> 4;   // grid = 32: 0-15 prod, 16-31 cons
    const int gblk = blockIdx.x & 15;
    if (role == 0)
        gru_body<E_SZ, true, 0>(xh, W_ih0, W_hh0, b_ih0, b_hh0, h1,
                                W_head, b_head, out, prog + gblk, gblk, hs[0], hs[1]);
    else
        gru_body<H_SZ, false, 1>(h1, W_ih1, W_hh1, b_ih1, b_hh1, nullptr,
                                 W_head, b_head, out, prog + gblk, gblk, hs[0], hs[1]);
}

__global__ __launch_bounds__(256)
void cvt_f32_f16(const float* __restrict__ in, _Float16* __restrict__ out, int n8)
{
    int i = blockIdx.x * 256 + threadIdx.x;
    if (i >= n8) return;
    const float4* p = (const float4*)in + (size_t)i * 2;
    float4 a = p[0];
    float4 b = p[1];
    half8 h;
    h[0] = (_Float16)a.x; h[1] = (_Float16)a.y; h[2] = (_Float16)a.z; h[3] = (_Float16)a.w;
    h[4] = (_Float16)b.x; h[5] = (_Float16)b.y; h[6] = (_Float16)b.z; h[7] = (_Float16)b.w;
    ((half8*)out)[i] = h;
}

extern "C" void kernel_launch(void* const* d_in, const int* in_sizes, int n_in,
                              void* d_out, int out_size, void* d_ws, size_t ws_size,
                              hipStream_t stream)
{
    const float* x      = (const float*)d_in[0];
    const float* W_ih0  = (const float*)d_in[1];
    const float* W_hh0  = (const float*)d_in[2];
    const float* b_ih0  = (const float*)d_in[3];
    const float* b_hh0  = (const float*)d_in[4];
    const float* W_ih1  = (const float*)d_in[5];
    const float* W_hh1  = (const float*)d_in[6];
    const float* b_ih1  = (const float*)d_in[7];
    const float* b_hh1  = (const float*)d_in[8];
    const float* W_head = (const float*)d_in[9];
    const float* b_head = (const float*)d_in[10];
    float* out = (float*)d_out;

    char* ws = (char*)d_ws;
    _Float16* h1  = (_Float16*)ws;                              // 64 MiB (B,T,128) fp16
    _Float16* xh  = (_Float16*)(ws + (64u << 20));              // 32 MiB (B,T,64)  fp16
    int*      prg = (int*)     (ws + (96u << 20));

    hipMemsetAsync(prg, 0, NBLK * sizeof(int), stream);
    cvt_f32_f16<<<(B_SZ * T_SZ * E_SZ / 8 + 255) / 256, 256, 0, stream>>>(x, xh, B_SZ * T_SZ * E_SZ / 8);
    gru_fused<<<2 * NBLK, 512, 0, stream>>>(xh, h1,
                                            W_ih0, W_hh0, b_ih0, b_hh0,
                                            W_ih1, W_hh1, b_ih1, b_hh1,
                                            W_head, b_head, out, prg);
}

// Round 13
// 514.351 us; speedup vs baseline: 8.5694x; 1.8901x over previous
//
#include <hip/hip_runtime.h>

// GRU_10746008175428 round 13: r9 restored (best: 512us) + residual micro-cuts.
// B=512 T=512 E=64 H=128 P=96.
// 64 blocks x 512 thr: blocks 0-31 layer0 (producer), 32-63 layer1 (consumer
// + fused head), paired per 16-row batch group. Agent acquire/release
// handoff. x pre-converted fp16. Weights resident in VGPRs (pre-scaled
// gates), h fp32 in regs + fp16 LDS exchange (swizzled, double-buffered),
// lgkm-only step barrier, r/z hh-MFMAs C-chained into x accumulators.
// vs r9: publish every 16 steps (was 8; halves vmcnt(0) full-drain events),
// s_sleep(1) polls (was 8; 64cy wake granularity).
// Lesson ledger: r6/r8 split-acc flat; r10/r11 1024-thr = 64-VGPR cap
// disaster; r12 dual-group serialized (compiler won't co-live 2 streams).

#define B_SZ 512
#define T_SZ 512
#define E_SZ 64
#define H_SZ 128
#define P_SZ 96
#define NB   16
#define NGRP (B_SZ / NB)          // 32
#define SC_SIG  (-1.44269504f)   // -log2(e)
#define SC_TANH (-2.88539008f)   // -2*log2(e)

typedef _Float16 half8 __attribute__((ext_vector_type(8)));
typedef float    f32x4 __attribute__((ext_vector_type(4)));

__device__ __forceinline__ float exp2_(float x) {
#if __has_builtin(__builtin_amdgcn_exp2f)
    return __builtin_amdgcn_exp2f(x);
#else
    return exp2f(x);
#endif
}
__device__ __forceinline__ float rcp_(float x) {
#if __has_builtin(__builtin_amdgcn_rcpf)
    return __builtin_amdgcn_rcpf(x);
#else
    return 1.0f / x;
#endif
}

// XOR-swizzled byte offset in a [rows][256B] LDS tile
__device__ __forceinline__ int swz256(int row, int byte) {
    return row * 256 + (byte ^ ((row & 7) << 4));
}

// One B-fragment (16 cols x 32 k) from fp32 weight matrix W, pre-scaled.
// lane: col n0+(ln&15), k = kt*32 + (ln>>4)*8 + j.
__device__ __forceinline__ void load_bfrag(const float* __restrict__ W, int ldk,
                                           int n0, int kt, int ln, float scale,
                                           half8* hi) {
    int n = n0 + (ln & 15);
    int k = kt * 32 + (ln >> 4) * 8;
    const float* p = W + (size_t)n * ldk + k;
    float4 a = *(const float4*)p;
    float4 b = *(const float4*)(p + 4);
    float v[8] = {a.x, a.y, a.z, a.w, b.x, b.y, b.z, b.w};
    half8 h;
    #pragma unroll
    for (int j = 0; j < 8; ++j)
        h[j] = (_Float16)(v[j] * scale);
    *hi = h;
}

#define LOADX(Sx, tt)                                                              \
    if ((tt) < T_SZ) {                                                             \
        _Pragma("unroll") for (int kt = 0; kt < KFX; ++kt)                         \
            Sx[kt] = *(const half8*)(xlane + (size_t)(tt) * ROWB + kt * 64);       \
    }

#define GRU_STEP(Sx, tcur, tnext)                                                  \
    {                                                                              \
        const char* hb = hs[(tcur) & 1];                                           \
        half8 ah[4];                                                               \
        _Pragma("unroll") for (int kt = 0; kt < 4; ++kt)                           \
            ah[kt] = *(const half8*)(hb + swz256(colg, kt * 64 + rgrp * 16));      \
        f32x4 ax0 = {bs0, bs0, bs0, bs0};                                          \
        f32x4 ax1 = {bs1, bs1, bs1, bs1};                                          \
        f32x4 ax2 = {bi2s, bi2s, bi2s, bi2s};                                      \
        f32x4 cNH = {bh2s, bh2s, bh2s, bh2s};                                      \
        _Pragma("unroll") for (int kt = 0; kt < KFX; ++kt) {                       \
            ax0 = __builtin_amdgcn_mfma_f32_16x16x32_f16(Sx[kt], bx[0][kt], ax0, 0, 0, 0); \
            ax1 = __builtin_amdgcn_mfma_f32_16x16x32_f16(Sx[kt], bx[1][kt], ax1, 0, 0, 0); \
            ax2 = __builtin_amdgcn_mfma_f32_16x16x32_f16(Sx[kt], bx[2][kt], ax2, 0, 0, 0); \
        }                                                                          \
        __builtin_amdgcn_s_setprio(1);                                             \
        _Pragma("unroll") for (int kt = 0; kt < 4; ++kt) {                         \
            ax0 = __builtin_amdgcn_mfma_f32_16x16x32_f16(ah[kt], bhh[0][kt], ax0, 0, 0, 0); \
            ax1 = __builtin_amdgcn_mfma_f32_16x16x32_f16(ah[kt], bhh[1][kt], ax1, 0, 0, 0); \
            cNH = __builtin_amdgcn_mfma_f32_16x16x32_f16(ah[kt], bhh[2][kt], cNH, 0, 0, 0); \
        }                                                                          \
        LOADX(Sx, tnext)                                                           \
        float hn_[4];                                                              \
        _Pragma("unroll") for (int j = 0; j < 4; ++j) {                            \
            float rr = rcp_(1.f + exp2_(ax0[j]));                                  \
            float zz = rcp_(1.f + exp2_(ax1[j]));                                  \
            float v  = ax2[j] + rr * cNH[j];                                       \
            float nn = fmaf(2.f, rcp_(1.f + exp2_(v)), -1.f);                      \
            hn_[j] = nn + zz * (hreg[j] - nn);                                     \
            hreg[j] = hn_[j];                                                      \
        }                                                                          \
        __builtin_amdgcn_s_setprio(0);                                             \
        char* hw = hs[((tcur) + 1) & 1];                                           \
        _Pragma("unroll") for (int j = 0; j < 4; ++j) {                            \
            int bb = rgrp * 4 + j;                                                 \
            *(_Float16*)(hw + swz256(bb, cw * 2)) = (_Float16)hn_[j];              \
            if constexpr (OUT_ALL) {                                               \
                ((_Float16*)hout)[((size_t)(b0 + bb) * T_SZ + (tcur)) * H_SZ + cw] \
                    = (_Float16)hn_[j];                                            \
            }                                                                      \
        }                                                                          \
        /* lgkm-only barrier: keep global loads/stores in flight across steps */   \
        asm volatile("s_waitcnt lgkmcnt(0)" ::: "memory");                         \
        __builtin_amdgcn_s_barrier();                                              \
        __builtin_amdgcn_sched_barrier(0);                                         \
    }

// ROLE 0 = producer (layer 0), ROLE 1 = consumer (layer 1 + fused head)
template<int K_IN, bool OUT_ALL, int ROLE>
__device__ __forceinline__ void gru_body(const _Float16* __restrict__ xin,
                                         const float* __restrict__ W_ih,
                                         const float* __restrict__ W_hh,
                                         const float* __restrict__ b_ih,
                                         const float* __restrict__ b_hh,
                                         void* __restrict__ hout,
                                         const float* __restrict__ W_head,
                                         const float* __restrict__ b_head,
                                         float* __restrict__ out,
                                         int* __restrict__ prog,
                                         int grp, char (*hs)[4096])
{
    constexpr int KFX  = K_IN / 32;
    constexpr int ROWB = K_IN * 2;     // fp16 row bytes

    const int tid  = threadIdx.x;
    const int ln   = tid & 63;
    const int wv   = tid >> 6;        // wave 0..7 -> col tile
    const int colg = ln & 15;
    const int rgrp = ln >> 4;
    const int b0   = grp * NB;
    const int cw   = wv * 16 + colg;  // hidden-unit column 0..127

    // ---- resident weight fragments (pre-scaled per gate) ----
    half8 bx[3][KFX];        // W_ih fp16
    half8 bhh[3][4];         // W_hh fp16
    const float gsc[3] = {SC_SIG, SC_SIG, SC_TANH};
    #pragma unroll
    for (int g = 0; g < 3; ++g) {
        int n0 = g * 128 + wv * 16;
        #pragma unroll
        for (int kt = 0; kt < KFX; ++kt)
            load_bfrag(W_ih, K_IN, n0, kt, ln, gsc[g], &bx[g][kt]);
        #pragma unroll
        for (int kt = 0; kt < 4; ++kt)
            load_bfrag(W_hh, H_SZ, n0, kt, ln, gsc[g], &bhh[g][kt]);
    }
    const float bs0  = SC_SIG  * (b_ih[cw] + b_hh[cw]);
    const float bs1  = SC_SIG  * (b_ih[128 + cw] + b_hh[128 + cw]);
    const float bi2s = SC_TANH * b_ih[256 + cw];
    const float bh2s = SC_TANH * b_hh[256 + cw];

    if (tid < 256) *(float4*)(hs[0] + tid * 16) = make_float4(0.f, 0.f, 0.f, 0.f);
    float hreg[4] = {0.f, 0.f, 0.f, 0.f};

    // per-lane x row base: A-row = colg (batch), k-offset rgrp*8 elems (16B)
    const char* xlane = (const char*)xin
        + (size_t)(b0 + colg) * T_SZ * ROWB
        + rgrp * 16;

    int avail = 0;
    if (ROLE == 1) {
        while (avail < 4) {
            avail = __hip_atomic_load(prog, __ATOMIC_ACQUIRE, __HIP_MEMORY_SCOPE_AGENT);
            if (avail < 4) __builtin_amdgcn_s_sleep(1);
        }
    }

    half8 Ax[KFX], Bx2[KFX];
    LOADX(Ax, 0)
    LOADX(Bx2, 1)
    __syncthreads();

    for (int t = 0; t < T_SZ; t += 2) {
        if (ROLE == 1 && avail < T_SZ) {
            const int need = (t + 4 < T_SZ) ? t + 4 : T_SZ;
            while (avail < need) {
                avail = __hip_atomic_load(prog, __ATOMIC_ACQUIRE, __HIP_MEMORY_SCOPE_AGENT);
                if (avail < need) __builtin_amdgcn_s_sleep(1);
            }
        }
        GRU_STEP(Ax,  t,     t + 2)
        GRU_STEP(Bx2, t + 1, t + 3)
        if (ROLE == 0 && (t & 15) == 14) {
            // publish progress every 16 steps: drain own stores -> block
            // barrier -> agent-scope release (final publish at t=510 -> 512)
            asm volatile("s_waitcnt vmcnt(0)" ::: "memory");
            __builtin_amdgcn_s_barrier();
            if (tid == 0)
                __hip_atomic_store(prog, t + 2, __ATOMIC_RELEASE, __HIP_MEMORY_SCOPE_AGENT);
        }
    }

    // ---- fused head (consumer only): out = h(T) @ W_head^T + b_head ----
    // hs[0] holds h(T) in A-frag layout (T_SZ even; last barrier passed).
    // W_head fragments loaded here (epilogue) so they are not live in-loop.
    if (ROLE == 1 && wv < 6) {
        half8 bph[4];
        #pragma unroll
        for (int kt = 0; kt < 4; ++kt)
            load_bfrag(W_head, H_SZ, wv * 16, kt, ln, 1.0f, &bph[kt]);
        const float bhd = b_head[cw];
        half8 ahf[4];
        #pragma unroll
        for (int kt = 0; kt < 4; ++kt)
            ahf[kt] = *(const half8*)(hs[0] + swz256(colg, kt * 64 + rgrp * 16));
        f32x4 acc = {bhd, bhd, bhd, bhd};
        #pragma unroll
        for (int kt = 0; kt < 4; ++kt)
            acc = __builtin_amdgcn_mfma_f32_16x16x32_f16(ahf[kt], bph[kt], acc, 0, 0, 0);
        #pragma unroll
        for (int j = 0; j < 4; ++j)
            out[(size_t)(b0 + rgrp * 4 + j) * P_SZ + cw] = acc[j];
    }
}

__global__ __launch_bounds__(512)
void gru_fused(const _Float16* __restrict__ xh,  // (B,T,64) fp16
               _Float16* __restrict__ h1,        // (B,T,128) fp16
               const float* __restrict__ W_ih0, const float* __restrict__ W_hh0,
               const float* __restrict__ b_ih0, const float* __restrict__ b_hh0,
               const float* __restrict__ W_ih1, const float* __restrict__ W_hh1,
               const float* __restrict__ b_ih1, const float* __restrict__ b_hh1,
               const float* __restrict__ W_head, const float* __restrict__ b_head,
               float* __restrict__ out,          // (B,96) f32
               int* __restrict__ prog)
{
    __shared__ __align__(16) char hs[2][4096];
    const int role = blockIdx.x >> 5;   // grid = 64
    const int grp  = blockIdx.x & 31;
    if (role == 0)
        gru_body<E_SZ, true, 0>(xh, W_ih0, W_hh0, b_ih0, b_hh0, h1,
                                W_head, b_head, out, prog + grp, grp, hs);
    else
        gru_body<H_SZ, false, 1>(h1, W_ih1, W_hh1, b_ih1, b_hh1, nullptr,
                                 W_head, b_head, out, prog + grp, grp, hs);
}

__global__ __launch_bounds__(256)
void cvt_f32_f16(const float* __restrict__ in, _Float16* __restrict__ out, int n8)
{
    int i = blockIdx.x * 256 + threadIdx.x;
    if (i >= n8) return;
    const float4* p = (const float4*)in + (size_t)i * 2;
    float4 a = p[0];
    float4 b = p[1];
    half8 h;
    h[0] = (_Float16)a.x; h[1] = (_Float16)a.y; h[2] = (_Float16)a.z; h[3] = (_Float16)a.w;
    h[4] = (_Float16)b.x; h[5] = (_Float16)b.y; h[6] = (_Float16)b.z; h[7] = (_Float16)b.w;
    ((half8*)out)[i] = h;
}

extern "C" void kernel_launch(void* const* d_in, const int* in_sizes, int n_in,
                              void* d_out, int out_size, void* d_ws, size_t ws_size,
                              hipStream_t stream)
{
    const float* x      = (const float*)d_in[0];
    const float* W_ih0  = (const float*)d_in[1];
    const float* W_hh0  = (const float*)d_in[2];
    const float* b_ih0  = (const float*)d_in[3];
    const float* b_hh0  = (const float*)d_in[4];
    const float* W_ih1  = (const float*)d_in[5];
    const float* W_hh1  = (const float*)d_in[6];
    const float* b_ih1  = (const float*)d_in[7];
    const float* b_hh1  = (const float*)d_in[8];
    const float* W_head = (const float*)d_in[9];
    const float* b_head = (const float*)d_in[10];
    float* out = (float*)d_out;

    char* ws = (char*)d_ws;
    _Float16* h1  = (_Float16*)ws;                              // 64 MiB (B,T,128) fp16
    _Float16* xh  = (_Float16*)(ws + (64u << 20));              // 32 MiB (B,T,64)  fp16
    int*      prg = (int*)     (ws + (96u << 20));

    hipMemsetAsync(prg, 0, NGRP * sizeof(int), stream);
    cvt_f32_f16<<<(B_SZ * T_SZ * E_SZ / 8 + 255) / 256, 256, 0, stream>>>(x, xh, B_SZ * T_SZ * E_SZ / 8);
    gru_fused<<<2 * NGRP, 512, 0, stream>>>(xh, h1,
                                            W_ih0, W_hh0, b_ih0, b_hh0,
                                            W_ih1, W_hh1, b_ih1, b_hh1,
                                            W_head, b_head, out, prg);
}